// Round 8
// baseline (398.904 us; speedup 1.0000x reference)
//
#include <hip/hip_runtime.h>
#include <hip/hip_bf16.h>
#include <hip/hip_cooperative_groups.h>
#include <math.h>

namespace cg = cooperative_groups;

#define NN 250000
#define CIN 32
#define COUT 32
#define KK 27
#define BN_EPS 1e-5f

typedef __attribute__((ext_vector_type(8))) short bf16x8;
typedef __attribute__((ext_vector_type(4))) float f32x4;

// ws layout (bytes):
//   [0, 512)        stats: ws_f[0..31]=sum, [32..63]=sumsq
//   [512, 55808)    packed bf16 weight: [k][h][lane][j]
//   [65536, +16MB)  bf16 x: [NN][32]
#define WS_WB_OFF   512
#define WS_XB_OFF   65536
#define WS_NEED     (WS_XB_OFF + (size_t)NN * CIN * 2)

#define CVT_CHUNKS  ((NN * CIN) / 8)
#define CVT_BLOCKS  ((CVT_CHUNKS + 255) / 256)
#define PACK_ELEMS  (KK * 2 * 64 * 8)
#define PACK_BLOCKS ((PACK_ELEMS + 255) / 256)

#define FUSED_BLOCKS ((NN + 127) / 128)   // 1954 <= 8 blocks/CU x 256 CU

static __device__ __forceinline__ unsigned short f2bf(float f) {
    unsigned int u = __float_as_uint(f);
    unsigned int r = (u + 0x7fffu + ((u >> 16) & 1u)) >> 16;  // RNE
    return (unsigned short)r;
}

// ---------------- prep: convert x -> bf16 AND pack w, one launch ----------------
__global__ __launch_bounds__(256) void prep_kernel(
    const float* __restrict__ x, unsigned short* __restrict__ xb,
    const float* __restrict__ w, unsigned short* __restrict__ wbp)
{
    int b = blockIdx.x;
    if (b < CVT_BLOCKS) {
        size_t i = (size_t)b * 256 + threadIdx.x;
        if (i >= CVT_CHUNKS) return;
        const float4* xp = (const float4*)x;
        float4 a = xp[i * 2], c = xp[i * 2 + 1];
        union { unsigned short u[8]; uint4 v; } o;
        o.u[0] = f2bf(a.x); o.u[1] = f2bf(a.y); o.u[2] = f2bf(a.z); o.u[3] = f2bf(a.w);
        o.u[4] = f2bf(c.x); o.u[5] = f2bf(c.y); o.u[6] = f2bf(c.z); o.u[7] = f2bf(c.w);
        ((uint4*)xb)[i] = o.v;
    } else {
        int tid = (b - CVT_BLOCKS) * 256 + threadIdx.x;
        if (tid >= PACK_ELEMS) return;
        int j = tid & 7;
        int l = (tid >> 3) & 63;
        int h = (tid >> 9) & 1;
        int k = tid >> 10;
        int c = (l >> 4) * 8 + j;
        int d = h * 16 + (l & 15);
        wbp[tid] = f2bf(w[k * (CIN * COUT) + c * COUT + d]);
    }
}

// ---------------- fused persistent kernel: conv + stats + gridsync + BN + ELU ----
// Inner loop = round-3's verbatim (proven 3.65 TB/s, VGPR 32): 32 nodes/wave,
// interleaved dual-row k-loop, LDS-staged indices, no intra-conv barriers.
// y held in acc registers across the grid sync; written exactly once.
__global__ __launch_bounds__(256, 8) void fused_kernel(
    const unsigned short* __restrict__ xb,
    const int* __restrict__ neigh,
    const unsigned short* __restrict__ wbp,
    const float* __restrict__ gamma,
    const float* __restrict__ beta,
    float* __restrict__ y,
    float* __restrict__ ws)
{
    __shared__ int lidx[128 * KK];     // 13824 B
    __shared__ float sred[4][2][16];
    __shared__ float qred[4][2][16];

    int b0 = blockIdx.x * 128;
    for (int t = threadIdx.x; t < 128 * KK; t += 256) {
        long long g = (long long)b0 * KK + t;
        lidx[t] = (g < (long long)NN * KK) ? neigh[g] : 0;
    }
    __syncthreads();

    int lane = threadIdx.x & 63;
    int wid  = threadIdx.x >> 6;
    int row  = lane & 15;   // A row within 16-tile / C col (channel within half)
    int grp  = lane >> 4;   // K chunk / C row group

    const int* lp0 = &lidx[(wid * 32 + row) * KK];
    const int* lp1 = &lidx[(wid * 32 + 16 + row) * KK];

    f32x4 acc[2][2];
#pragma unroll
    for (int t = 0; t < 2; ++t)
#pragma unroll
        for (int h = 0; h < 2; ++h) acc[t][h] = (f32x4){0.f, 0.f, 0.f, 0.f};

    const bf16x8* wbv = (const bf16x8*)wbp;

#pragma unroll
    for (int k = 0; k < KK; ++k) {
        int id0 = lp0[k];
        int id1 = lp1[k];
        bf16x8 a0 = *(const bf16x8*)(xb + (size_t)id0 * CIN + grp * 8);
        bf16x8 a1 = *(const bf16x8*)(xb + (size_t)id1 * CIN + grp * 8);
        bf16x8 vb0 = wbv[(k * 2 + 0) * 64 + lane];
        bf16x8 vb1 = wbv[(k * 2 + 1) * 64 + lane];
        acc[0][0] = __builtin_amdgcn_mfma_f32_16x16x32_bf16(a0, vb0, acc[0][0], 0, 0, 0);
        acc[0][1] = __builtin_amdgcn_mfma_f32_16x16x32_bf16(a0, vb1, acc[0][1], 0, 0, 0);
        acc[1][0] = __builtin_amdgcn_mfma_f32_16x16x32_bf16(a1, vb0, acc[1][0], 0, 0, 0);
        acc[1][1] = __builtin_amdgcn_mfma_f32_16x16x32_bf16(a1, vb1, acc[1][1], 0, 0, 0);
    }

    // ---- per-channel stats (C row = grp*4 + i) ----
    int base = b0 + wid * 32;
    float s0 = 0.f, q0 = 0.f, s1 = 0.f, q1 = 0.f;
#pragma unroll
    for (int t = 0; t < 2; ++t) {
#pragma unroll
        for (int i = 0; i < 4; ++i) {
            int node = base + t * 16 + grp * 4 + i;
            if (node < NN) {
                float v0 = acc[t][0][i], v1 = acc[t][1][i];
                s0 += v0; q0 += v0 * v0;
                s1 += v1; q1 += v1 * v1;
            }
        }
    }
    s0 += __shfl_xor(s0, 16); s0 += __shfl_xor(s0, 32);
    q0 += __shfl_xor(q0, 16); q0 += __shfl_xor(q0, 32);
    s1 += __shfl_xor(s1, 16); s1 += __shfl_xor(s1, 32);
    q1 += __shfl_xor(q1, 16); q1 += __shfl_xor(q1, 32);

    if (lane < 16) {
        sred[wid][0][row] = s0; qred[wid][0][row] = q0;
        sred[wid][1][row] = s1; qred[wid][1][row] = q1;
    }
    __syncthreads();
    if (threadIdx.x < 32) {
        int h = threadIdx.x >> 4, c = threadIdx.x & 15;
        float S = 0.f, Q = 0.f;
#pragma unroll
        for (int wv = 0; wv < 4; ++wv) { S += sred[wv][h][c]; Q += qred[wv][h][c]; }
        atomicAdd(&ws[h * 16 + c], S);
        atomicAdd(&ws[32 + h * 16 + c], Q);
    }

    cg::this_grid().sync();

    // ---- finalize for this thread's two channels (row, 16+row) ----
    float invN = 1.0f / (float)NN;
    float m0  = ws[row] * invN;
    float va0 = ws[32 + row] * invN - m0 * m0;
    float sc0 = rsqrtf(va0 + BN_EPS) * gamma[row];
    float sh0 = beta[row] - m0 * sc0;
    float m1  = ws[16 + row] * invN;
    float va1 = ws[48 + row] * invN - m1 * m1;
    float sc1 = rsqrtf(va1 + BN_EPS) * gamma[16 + row];
    float sh1 = beta[16 + row] - m1 * sc1;

    // ---- BN + ELU on register-held y, single write ----
#pragma unroll
    for (int t = 0; t < 2; ++t) {
#pragma unroll
        for (int i = 0; i < 4; ++i) {
            int node = base + t * 16 + grp * 4 + i;
            if (node < NN) {
                float a0 = acc[t][0][i] * sc0 + sh0;
                float a1 = acc[t][1][i] * sc1 + sh1;
                a0 = (a0 > 0.0f) ? a0 : expm1f(a0);
                a1 = (a1 > 0.0f) ? a1 : expm1f(a1);
                y[(size_t)node * COUT + row]      = a0;
                y[(size_t)node * COUT + 16 + row] = a1;
            }
        }
    }
}

// ---------------- fp32 fallback path (ws too small / coop launch failed) -------
__global__ __launch_bounds__(256) void conv_kernel(
    const float* __restrict__ x, const int* __restrict__ neigh,
    const float* __restrict__ w, float* __restrict__ y)
{
    int n = blockIdx.x * 256 + threadIdx.x;
    bool valid = (n < NN);
    int nsafe = valid ? n : 0;
    int idx[KK];
#pragma unroll
    for (int k = 0; k < KK; ++k) idx[k] = neigh[(size_t)nsafe * KK + k];
    float acc[COUT];
#pragma unroll
    for (int d = 0; d < COUT; ++d) acc[d] = 0.0f;
    for (int k = 0; k < KK; ++k) {
        const float4* xr = (const float4*)(x + (size_t)idx[k] * CIN);
        float4 xv[8];
#pragma unroll
        for (int j = 0; j < 8; ++j) xv[j] = xr[j];
        const float* wk = w + k * (CIN * COUT);
        const float* xs = (const float*)xv;
#pragma unroll
        for (int c = 0; c < CIN; ++c) {
            float xc = xs[c];
#pragma unroll
            for (int d = 0; d < COUT; ++d)
                acc[d] = fmaf(xc, wk[c * COUT + d], acc[d]);
        }
    }
    if (valid) {
        float4* yr = (float4*)(y + (size_t)n * COUT);
#pragma unroll
        for (int j = 0; j < 8; ++j) {
            float4 v;
            v.x = acc[j*4+0]; v.y = acc[j*4+1]; v.z = acc[j*4+2]; v.w = acc[j*4+3];
            yr[j] = v;
        }
    }
}

__global__ __launch_bounds__(256) void stats_kernel(
    const float* __restrict__ y, float* __restrict__ ws)
{
    int d = threadIdx.x & 31;
    int rib = threadIdx.x >> 5;
    float s = 0.0f, q = 0.0f;
    for (int r = blockIdx.x * 8 + rib; r < NN; r += gridDim.x * 8) {
        float v = y[(size_t)r * COUT + d];
        s += v;
        q += v * v;
    }
    __shared__ float ls[8][32];
    __shared__ float lq[8][32];
    ls[rib][d] = s;
    lq[rib][d] = q;
    __syncthreads();
    if (threadIdx.x < 32) {
        float S = 0.0f, Q = 0.0f;
#pragma unroll
        for (int i = 0; i < 8; ++i) { S += ls[i][threadIdx.x]; Q += lq[i][threadIdx.x]; }
        atomicAdd(&ws[threadIdx.x], S);
        atomicAdd(&ws[32 + threadIdx.x], Q);
    }
}

__global__ void finalize_kernel(
    const float* __restrict__ gamma, const float* __restrict__ beta,
    float* __restrict__ ws)
{
    int d = threadIdx.x;
    if (d < 32) {
        float invN = 1.0f / (float)NN;
        float mean = ws[d] * invN;
        float var = ws[32 + d] * invN - mean * mean;
        float rstd = rsqrtf(var + BN_EPS);
        float scale = rstd * gamma[d];
        ws[64 + d] = scale;
        ws[96 + d] = beta[d] - mean * scale;
    }
}

__global__ __launch_bounds__(256) void bn_elu_kernel(
    float* __restrict__ y, const float* __restrict__ ws)
{
    __shared__ float sc[32], sh[32];
    if (threadIdx.x < 32) {
        sc[threadIdx.x] = ws[64 + threadIdx.x];
        sh[threadIdx.x] = ws[96 + threadIdx.x];
    }
    __syncthreads();
    size_t i = (size_t)blockIdx.x * 256 + threadIdx.x;
    size_t total = (size_t)NN * COUT / 4;
    if (i >= total) return;
    int c0 = (int)((i * 4) & 31);
    float4 v = ((const float4*)y)[i];
    float r[4] = {v.x, v.y, v.z, v.w};
#pragma unroll
    for (int j = 0; j < 4; ++j) {
        float t = r[j] * sc[c0 + j] + sh[c0 + j];
        r[j] = (t > 0.0f) ? t : expm1f(t);
    }
    float4 o; o.x = r[0]; o.y = r[1]; o.z = r[2]; o.w = r[3];
    ((float4*)y)[i] = o;
}

extern "C" void kernel_launch(void* const* d_in, const int* in_sizes, int n_in,
                              void* d_out, int out_size, void* d_ws, size_t ws_size,
                              hipStream_t stream) {
    const float* x     = (const float*)d_in[0];
    const int*   neigh = (const int*)d_in[1];
    const float* w     = (const float*)d_in[2];
    const float* gamma = (const float*)d_in[3];
    const float* beta  = (const float*)d_in[4];
    float* y  = (float*)d_out;
    float* ws = (float*)d_ws;

    hipMemsetAsync(ws, 0, 512, stream);

    if (ws_size >= WS_NEED) {
        unsigned short* wbp = (unsigned short*)((char*)d_ws + WS_WB_OFF);
        unsigned short* xb  = (unsigned short*)((char*)d_ws + WS_XB_OFF);

        prep_kernel<<<CVT_BLOCKS + PACK_BLOCKS, 256, 0, stream>>>(x, xb, w, wbp);

        const unsigned short* xbc = xb;
        const unsigned short* wbc = wbp;
        void* args[7];
        args[0] = (void*)&xbc;
        args[1] = (void*)&neigh;
        args[2] = (void*)&wbc;
        args[3] = (void*)&gamma;
        args[4] = (void*)&beta;
        args[5] = (void*)&y;
        args[6] = (void*)&ws;
        hipError_t e = hipLaunchCooperativeKernel((const void*)fused_kernel,
                                                  dim3(FUSED_BLOCKS), dim3(256),
                                                  args, 0, stream);
        if (e == hipSuccess) return;
        // cooperative launch unavailable -> fall through to fp32 path
    }

    int convBlocks = (NN + 255) / 256;
    conv_kernel<<<convBlocks, 256, 0, stream>>>(x, neigh, w, y);
    stats_kernel<<<512, 256, 0, stream>>>(y, ws);
    finalize_kernel<<<1, 32, 0, stream>>>(gamma, beta, ws);
    size_t total4 = (size_t)NN * COUT / 4;
    bn_elu_kernel<<<(int)((total4 + 255) / 256), 256, 0, stream>>>(y, ws);
}

// Round 9
// 157.208 us; speedup vs baseline: 2.5374x; 2.5374x over previous
//
#include <hip/hip_runtime.h>
#include <hip/hip_bf16.h>
#include <math.h>

#define NN 250000
#define CIN 32
#define COUT 32
#define KK 27
#define BN_EPS 1e-5f

typedef __attribute__((ext_vector_type(8))) short bf16x8;
typedef __attribute__((ext_vector_type(4))) float f32x4;

// ws layout (bytes):
//   [0, 512)        stats: ws_f[0..31]=sum, [32..63]=sumsq, [64..95]=scale, [96..127]=shift
//   [512, 55808)    packed bf16 weight: [k][h][lane][j]  (27*2*64*8 ushorts)
//   [65536, +16MB)  bf16 x: [NN][32]
#define WS_WB_OFF   512
#define WS_XB_OFF   65536
#define WS_NEED     (WS_XB_OFF + (size_t)NN * CIN * 2)

#define CVT_CHUNKS  ((NN * CIN) / 8)                     // 1,000,000
#define CVT_BLOCKS  ((CVT_CHUNKS + 255) / 256)           // 3907
#define PACK_ELEMS  (KK * 2 * 64 * 8)                    // 27648
#define PACK_BLOCKS ((PACK_ELEMS + 255) / 256)           // 108

static __device__ __forceinline__ unsigned short f2bf(float f) {
    unsigned int u = __float_as_uint(f);
    unsigned int r = (u + 0x7fffu + ((u >> 16) & 1u)) >> 16;  // RNE
    return (unsigned short)r;
}

// ---------------- prep: convert x -> bf16 AND pack w, one launch ----------------
__global__ __launch_bounds__(256) void prep_kernel(
    const float* __restrict__ x, unsigned short* __restrict__ xb,
    const float* __restrict__ w, unsigned short* __restrict__ wbp)
{
    int b = blockIdx.x;
    if (b < CVT_BLOCKS) {
        size_t i = (size_t)b * 256 + threadIdx.x;
        if (i >= CVT_CHUNKS) return;
        const float4* xp = (const float4*)x;
        float4 a = xp[i * 2], c = xp[i * 2 + 1];
        union { unsigned short u[8]; uint4 v; } o;
        o.u[0] = f2bf(a.x); o.u[1] = f2bf(a.y); o.u[2] = f2bf(a.z); o.u[3] = f2bf(a.w);
        o.u[4] = f2bf(c.x); o.u[5] = f2bf(c.y); o.u[6] = f2bf(c.z); o.u[7] = f2bf(c.w);
        ((uint4*)xb)[i] = o.v;
    } else {
        int tid = (b - CVT_BLOCKS) * 256 + threadIdx.x;
        if (tid >= PACK_ELEMS) return;
        int j = tid & 7;
        int l = (tid >> 3) & 63;
        int h = (tid >> 9) & 1;
        int k = tid >> 10;
        int c = (l >> 4) * 8 + j;
        int d = h * 16 + (l & 15);
        wbp[tid] = f2bf(w[k * (CIN * COUT) + c * COUT + d]);
    }
}

// ---------------- MFMA conv (round-2 exact structure) + fused stats ----------
// 64 nodes/block, 4 waves x 16 nodes, LDS-staged indices, simple k-loop.
// Proven 102us / 3.66 TB/s / VGPR 48. Epilogue adds per-channel sum/sumsq
// (proven correct in r5/r6 at this shape) -> deletes the stats pass.
__global__ __launch_bounds__(256) void conv_mfma_kernel(
    const unsigned short* __restrict__ xb,
    const int* __restrict__ neigh,
    const unsigned short* __restrict__ wbp,
    float* __restrict__ y,
    float* __restrict__ ws)
{
    __shared__ int lidx[64 * KK];
    int b0 = blockIdx.x * 64;
    for (int t = threadIdx.x; t < 64 * KK; t += 256) {
        long long g = (long long)b0 * KK + t;
        lidx[t] = (g < (long long)NN * KK) ? neigh[g] : 0;
    }
    __syncthreads();

    int lane = threadIdx.x & 63;
    int wid  = threadIdx.x >> 6;
    int row  = lane & 15;   // A row within tile / C col (channel within half)
    int grp  = lane >> 4;   // K chunk / C row group
    int nl   = wid * 16 + row;

    f32x4 acc0 = {0.f, 0.f, 0.f, 0.f};
    f32x4 acc1 = {0.f, 0.f, 0.f, 0.f};
    const bf16x8* wb = (const bf16x8*)wbp;

#pragma unroll
    for (int k = 0; k < KK; ++k) {
        int nidx = lidx[nl * KK + k];
        bf16x8 a = *(const bf16x8*)(xb + (size_t)nidx * CIN + grp * 8);
        bf16x8 bb0 = wb[(k * 2 + 0) * 64 + lane];
        bf16x8 bb1 = wb[(k * 2 + 1) * 64 + lane];
        acc0 = __builtin_amdgcn_mfma_f32_16x16x32_bf16(a, bb0, acc0, 0, 0, 0);
        acc1 = __builtin_amdgcn_mfma_f32_16x16x32_bf16(a, bb1, acc1, 0, 0, 0);
    }

    // ---- epilogue: y write + fused per-channel stats ----
    // C/D layout: col = lane&15, row = (lane>>4)*4 + reg
    int base = b0 + wid * 16;
    float s0 = 0.f, q0 = 0.f, s1 = 0.f, q1 = 0.f;
#pragma unroll
    for (int i = 0; i < 4; ++i) {
        int node = base + grp * 4 + i;
        float v0 = acc0[i], v1 = acc1[i];
        if (node < NN) {
            y[(size_t)node * COUT + row]      = v0;
            y[(size_t)node * COUT + 16 + row] = v1;
            s0 += v0; q0 += v0 * v0;
            s1 += v1; q1 += v1 * v1;
        }
    }
    s0 += __shfl_xor(s0, 16); s0 += __shfl_xor(s0, 32);
    q0 += __shfl_xor(q0, 16); q0 += __shfl_xor(q0, 32);
    s1 += __shfl_xor(s1, 16); s1 += __shfl_xor(s1, 32);
    q1 += __shfl_xor(q1, 16); q1 += __shfl_xor(q1, 32);

    __shared__ float sred[4][2][16];
    __shared__ float qred[4][2][16];
    if (lane < 16) {
        sred[wid][0][row] = s0; qred[wid][0][row] = q0;
        sred[wid][1][row] = s1; qred[wid][1][row] = q1;
    }
    __syncthreads();
    if (threadIdx.x < 32) {
        int h = threadIdx.x >> 4, c = threadIdx.x & 15;
        float S = 0.f, Q = 0.f;
#pragma unroll
        for (int wv = 0; wv < 4; ++wv) { S += sred[wv][h][c]; Q += qred[wv][h][c]; }
        atomicAdd(&ws[h * 16 + c], S);
        atomicAdd(&ws[32 + h * 16 + c], Q);
    }
}

// ---------------- fp32 fallback path (ws too small) ----------------
__global__ __launch_bounds__(256) void conv_kernel(
    const float* __restrict__ x, const int* __restrict__ neigh,
    const float* __restrict__ w, float* __restrict__ y)
{
    int n = blockIdx.x * 256 + threadIdx.x;
    bool valid = (n < NN);
    int nsafe = valid ? n : 0;
    int idx[KK];
#pragma unroll
    for (int k = 0; k < KK; ++k) idx[k] = neigh[(size_t)nsafe * KK + k];
    float acc[COUT];
#pragma unroll
    for (int d = 0; d < COUT; ++d) acc[d] = 0.0f;
    for (int k = 0; k < KK; ++k) {
        const float4* xr = (const float4*)(x + (size_t)idx[k] * CIN);
        float4 xv[8];
#pragma unroll
        for (int j = 0; j < 8; ++j) xv[j] = xr[j];
        const float* wk = w + k * (CIN * COUT);
        const float* xs = (const float*)xv;
#pragma unroll
        for (int c = 0; c < CIN; ++c) {
            float xc = xs[c];
#pragma unroll
            for (int d = 0; d < COUT; ++d)
                acc[d] = fmaf(xc, wk[c * COUT + d], acc[d]);
        }
    }
    if (valid) {
        float4* yr = (float4*)(y + (size_t)n * COUT);
#pragma unroll
        for (int j = 0; j < 8; ++j) {
            float4 v;
            v.x = acc[j*4+0]; v.y = acc[j*4+1]; v.z = acc[j*4+2]; v.w = acc[j*4+3];
            yr[j] = v;
        }
    }
}

__global__ __launch_bounds__(256) void stats_kernel(
    const float* __restrict__ y, float* __restrict__ ws)
{
    int d = threadIdx.x & 31;
    int rib = threadIdx.x >> 5;
    float s = 0.0f, q = 0.0f;
    for (int r = blockIdx.x * 8 + rib; r < NN; r += gridDim.x * 8) {
        float v = y[(size_t)r * COUT + d];
        s += v;
        q += v * v;
    }
    __shared__ float ls[8][32];
    __shared__ float lq[8][32];
    ls[rib][d] = s;
    lq[rib][d] = q;
    __syncthreads();
    if (threadIdx.x < 32) {
        float S = 0.0f, Q = 0.0f;
#pragma unroll
        for (int i = 0; i < 8; ++i) { S += ls[i][threadIdx.x]; Q += lq[i][threadIdx.x]; }
        atomicAdd(&ws[threadIdx.x], S);
        atomicAdd(&ws[32 + threadIdx.x], Q);
    }
}

// ---------------- finalize scale/shift ----------------
__global__ void finalize_kernel(
    const float* __restrict__ gamma, const float* __restrict__ beta,
    float* __restrict__ ws)
{
    int d = threadIdx.x;
    if (d < 32) {
        float invN = 1.0f / (float)NN;
        float mean = ws[d] * invN;
        float var = ws[32 + d] * invN - mean * mean;
        float rstd = rsqrtf(var + BN_EPS);
        float scale = rstd * gamma[d];
        ws[64 + d] = scale;
        ws[96 + d] = beta[d] - mean * scale;
    }
}

// ---------------- BN + ELU in place ----------------
__global__ __launch_bounds__(256) void bn_elu_kernel(
    float* __restrict__ y, const float* __restrict__ ws)
{
    __shared__ float sc[32], sh[32];
    if (threadIdx.x < 32) {
        sc[threadIdx.x] = ws[64 + threadIdx.x];
        sh[threadIdx.x] = ws[96 + threadIdx.x];
    }
    __syncthreads();
    size_t i = (size_t)blockIdx.x * 256 + threadIdx.x;
    size_t total = (size_t)NN * COUT / 4;
    if (i >= total) return;
    int c0 = (int)((i * 4) & 31);
    float4 v = ((const float4*)y)[i];
    float r[4] = {v.x, v.y, v.z, v.w};
#pragma unroll
    for (int j = 0; j < 4; ++j) {
        float t = r[j] * sc[c0 + j] + sh[c0 + j];
        r[j] = (t > 0.0f) ? t : expm1f(t);
    }
    float4 o; o.x = r[0]; o.y = r[1]; o.z = r[2]; o.w = r[3];
    ((float4*)y)[i] = o;
}

extern "C" void kernel_launch(void* const* d_in, const int* in_sizes, int n_in,
                              void* d_out, int out_size, void* d_ws, size_t ws_size,
                              hipStream_t stream) {
    const float* x     = (const float*)d_in[0];
    const int*   neigh = (const int*)d_in[1];
    const float* w     = (const float*)d_in[2];
    const float* gamma = (const float*)d_in[3];
    const float* beta  = (const float*)d_in[4];
    float* y  = (float*)d_out;
    float* ws = (float*)d_ws;

    hipMemsetAsync(ws, 0, 512, stream);

    if (ws_size >= WS_NEED) {
        unsigned short* wbp = (unsigned short*)((char*)d_ws + WS_WB_OFF);
        unsigned short* xb  = (unsigned short*)((char*)d_ws + WS_XB_OFF);

        prep_kernel<<<CVT_BLOCKS + PACK_BLOCKS, 256, 0, stream>>>(x, xb, w, wbp);

        int convBlocks = (NN + 63) / 64;
        conv_mfma_kernel<<<convBlocks, 256, 0, stream>>>(xb, neigh, wbp, y, ws);
    } else {
        int convBlocks = (NN + 255) / 256;
        conv_kernel<<<convBlocks, 256, 0, stream>>>(x, neigh, w, y);
        stats_kernel<<<512, 256, 0, stream>>>(y, ws);
    }

    finalize_kernel<<<1, 32, 0, stream>>>(gamma, beta, ws);

    size_t total4 = (size_t)NN * COUT / 4;
    bn_elu_kernel<<<(int)((total4 + 255) / 256), 256, 0, stream>>>(y, ws);
}

// Round 10
// 131.146 us; speedup vs baseline: 3.0417x; 1.1987x over previous
//
#include <hip/hip_runtime.h>
#include <hip/hip_bf16.h>
#include <math.h>

#define NN 250000
#define CIN 32
#define COUT 32
#define KK 27
#define BN_EPS 1e-5f

typedef __attribute__((ext_vector_type(8))) short bf16x8;
typedef __attribute__((ext_vector_type(4))) float f32x4;

// ws layout (bytes):
//   [512, 55808)    packed bf16 weight: [k][h][lane][j]  (27*2*64*8 ushorts)
//   [57344, 65536)  slotted stats: 32 slot-sets x 64 floats
//                   (slot*64 + c = sum, slot*64 + 32 + c = sumsq)
//   [65536, +16MB)  bf16 x: [NN][32]
#define WS_WB_OFF   512
#define WS_STAT_OFF 57344
#define NSLOTS      32
#define WS_XB_OFF   65536
#define WS_NEED     (WS_XB_OFF + (size_t)NN * CIN * 2)

#define CVT_CHUNKS  ((NN * CIN) / 8)                     // 1,000,000
#define CVT_BLOCKS  ((CVT_CHUNKS + 255) / 256)           // 3907
#define PACK_ELEMS  (KK * 2 * 64 * 8)                    // 27648
#define PACK_BLOCKS ((PACK_ELEMS + 255) / 256)           // 108

static __device__ __forceinline__ unsigned short f2bf(float f) {
    unsigned int u = __float_as_uint(f);
    unsigned int r = (u + 0x7fffu + ((u >> 16) & 1u)) >> 16;  // RNE
    return (unsigned short)r;
}

// ---------------- prep: convert x -> bf16 AND pack w, one launch ----------------
__global__ __launch_bounds__(256) void prep_kernel(
    const float* __restrict__ x, unsigned short* __restrict__ xb,
    const float* __restrict__ w, unsigned short* __restrict__ wbp)
{
    int b = blockIdx.x;
    if (b < CVT_BLOCKS) {
        size_t i = (size_t)b * 256 + threadIdx.x;
        if (i >= CVT_CHUNKS) return;
        const float4* xp = (const float4*)x;
        float4 a = xp[i * 2], c = xp[i * 2 + 1];
        union { unsigned short u[8]; uint4 v; } o;
        o.u[0] = f2bf(a.x); o.u[1] = f2bf(a.y); o.u[2] = f2bf(a.z); o.u[3] = f2bf(a.w);
        o.u[4] = f2bf(c.x); o.u[5] = f2bf(c.y); o.u[6] = f2bf(c.z); o.u[7] = f2bf(c.w);
        ((uint4*)xb)[i] = o.v;
    } else {
        int tid = (b - CVT_BLOCKS) * 256 + threadIdx.x;
        if (tid >= PACK_ELEMS) return;
        int j = tid & 7;
        int l = (tid >> 3) & 63;
        int h = (tid >> 9) & 1;
        int k = tid >> 10;
        int c = (l >> 4) * 8 + j;
        int d = h * 16 + (l & 15);
        wbp[tid] = f2bf(w[k * (CIN * COUT) + c * COUT + d]);
    }
}

// ---------------- MFMA conv (round-2 exact structure) + fused slotted stats ---
// 64 nodes/block, 4 waves x 16 nodes, LDS-staged indices, simple k-loop.
// Stats atomics spread over 32 slot-sets to kill line contention.
__global__ __launch_bounds__(256) void conv_mfma_kernel(
    const unsigned short* __restrict__ xb,
    const int* __restrict__ neigh,
    const unsigned short* __restrict__ wbp,
    float* __restrict__ y,
    float* __restrict__ st)     // slotted stats base
{
    __shared__ int lidx[64 * KK];
    int b0 = blockIdx.x * 64;
    for (int t = threadIdx.x; t < 64 * KK; t += 256) {
        long long g = (long long)b0 * KK + t;
        lidx[t] = (g < (long long)NN * KK) ? neigh[g] : 0;
    }
    __syncthreads();

    int lane = threadIdx.x & 63;
    int wid  = threadIdx.x >> 6;
    int row  = lane & 15;   // A row within tile / C col (channel within half)
    int grp  = lane >> 4;   // K chunk / C row group
    int nl   = wid * 16 + row;

    f32x4 acc0 = {0.f, 0.f, 0.f, 0.f};
    f32x4 acc1 = {0.f, 0.f, 0.f, 0.f};
    const bf16x8* wb = (const bf16x8*)wbp;

#pragma unroll
    for (int k = 0; k < KK; ++k) {
        int nidx = lidx[nl * KK + k];
        bf16x8 a = *(const bf16x8*)(xb + (size_t)nidx * CIN + grp * 8);
        bf16x8 bb0 = wb[(k * 2 + 0) * 64 + lane];
        bf16x8 bb1 = wb[(k * 2 + 1) * 64 + lane];
        acc0 = __builtin_amdgcn_mfma_f32_16x16x32_bf16(a, bb0, acc0, 0, 0, 0);
        acc1 = __builtin_amdgcn_mfma_f32_16x16x32_bf16(a, bb1, acc1, 0, 0, 0);
    }

    // ---- epilogue: y write + fused per-channel stats ----
    // C/D layout: col = lane&15, row = (lane>>4)*4 + reg
    int base = b0 + wid * 16;
    float s0 = 0.f, q0 = 0.f, s1 = 0.f, q1 = 0.f;
#pragma unroll
    for (int i = 0; i < 4; ++i) {
        int node = base + grp * 4 + i;
        float v0 = acc0[i], v1 = acc1[i];
        if (node < NN) {
            y[(size_t)node * COUT + row]      = v0;
            y[(size_t)node * COUT + 16 + row] = v1;
            s0 += v0; q0 += v0 * v0;
            s1 += v1; q1 += v1 * v1;
        }
    }
    s0 += __shfl_xor(s0, 16); s0 += __shfl_xor(s0, 32);
    q0 += __shfl_xor(q0, 16); q0 += __shfl_xor(q0, 32);
    s1 += __shfl_xor(s1, 16); s1 += __shfl_xor(s1, 32);
    q1 += __shfl_xor(q1, 16); q1 += __shfl_xor(q1, 32);

    __shared__ float sred[4][2][16];
    __shared__ float qred[4][2][16];
    if (lane < 16) {
        sred[wid][0][row] = s0; qred[wid][0][row] = q0;
        sred[wid][1][row] = s1; qred[wid][1][row] = q1;
    }
    __syncthreads();
    if (threadIdx.x < 32) {
        int h = threadIdx.x >> 4, c = threadIdx.x & 15;
        float S = 0.f, Q = 0.f;
#pragma unroll
        for (int wv = 0; wv < 4; ++wv) { S += sred[wv][h][c]; Q += qred[wv][h][c]; }
        int slot = blockIdx.x & (NSLOTS - 1);
        atomicAdd(&st[slot * 64 + h * 16 + c], S);
        atomicAdd(&st[slot * 64 + 32 + h * 16 + c], Q);
    }
}

// ---------------- fp32 fallback path (ws too small) ----------------
__global__ __launch_bounds__(256) void conv_kernel(
    const float* __restrict__ x, const int* __restrict__ neigh,
    const float* __restrict__ w, float* __restrict__ y)
{
    int n = blockIdx.x * 256 + threadIdx.x;
    bool valid = (n < NN);
    int nsafe = valid ? n : 0;
    int idx[KK];
#pragma unroll
    for (int k = 0; k < KK; ++k) idx[k] = neigh[(size_t)nsafe * KK + k];
    float acc[COUT];
#pragma unroll
    for (int d = 0; d < COUT; ++d) acc[d] = 0.0f;
    for (int k = 0; k < KK; ++k) {
        const float4* xr = (const float4*)(x + (size_t)idx[k] * CIN);
        float4 xv[8];
#pragma unroll
        for (int j = 0; j < 8; ++j) xv[j] = xr[j];
        const float* wk = w + k * (CIN * COUT);
        const float* xs = (const float*)xv;
#pragma unroll
        for (int c = 0; c < CIN; ++c) {
            float xc = xs[c];
#pragma unroll
            for (int d = 0; d < COUT; ++d)
                acc[d] = fmaf(xc, wk[c * COUT + d], acc[d]);
        }
    }
    if (valid) {
        float4* yr = (float4*)(y + (size_t)n * COUT);
#pragma unroll
        for (int j = 0; j < 8; ++j) {
            float4 v;
            v.x = acc[j*4+0]; v.y = acc[j*4+1]; v.z = acc[j*4+2]; v.w = acc[j*4+3];
            yr[j] = v;
        }
    }
}

__global__ __launch_bounds__(256) void stats_kernel(
    const float* __restrict__ y, float* __restrict__ st)
{
    int d = threadIdx.x & 31;
    int rib = threadIdx.x >> 5;
    float s = 0.0f, q = 0.0f;
    for (int r = blockIdx.x * 8 + rib; r < NN; r += gridDim.x * 8) {
        float v = y[(size_t)r * COUT + d];
        s += v;
        q += v * v;
    }
    __shared__ float ls[8][32];
    __shared__ float lq[8][32];
    ls[rib][d] = s;
    lq[rib][d] = q;
    __syncthreads();
    if (threadIdx.x < 32) {
        float S = 0.0f, Q = 0.0f;
#pragma unroll
        for (int i = 0; i < 8; ++i) { S += ls[i][threadIdx.x]; Q += lq[i][threadIdx.x]; }
        int slot = blockIdx.x & (NSLOTS - 1);
        atomicAdd(&st[slot * 64 + threadIdx.x], S);
        atomicAdd(&st[slot * 64 + 32 + threadIdx.x], Q);
    }
}

// ---------------- BN + ELU in place (finalize folded in) ----------------
__global__ __launch_bounds__(256) void bn_elu_kernel(
    float* __restrict__ y, const float* __restrict__ st,
    const float* __restrict__ gamma, const float* __restrict__ beta)
{
    __shared__ float sc[32], sh[32];
    if (threadIdx.x < 32) {
        int c = threadIdx.x;
        float S = 0.f, Q = 0.f;
#pragma unroll
        for (int sl = 0; sl < NSLOTS; ++sl) {
            S += st[sl * 64 + c];
            Q += st[sl * 64 + 32 + c];
        }
        float invN = 1.0f / (float)NN;
        float mean = S * invN;
        float var  = Q * invN - mean * mean;
        float scale = rsqrtf(var + BN_EPS) * gamma[c];
        sc[c] = scale;
        sh[c] = beta[c] - mean * scale;
    }
    __syncthreads();
    size_t i = (size_t)blockIdx.x * 256 + threadIdx.x;
    size_t total = (size_t)NN * COUT / 4;
    if (i >= total) return;
    int c0 = (int)((i * 4) & 31);
    float4 v = ((const float4*)y)[i];
    float r[4] = {v.x, v.y, v.z, v.w};
#pragma unroll
    for (int j = 0; j < 4; ++j) {
        float t = r[j] * sc[c0 + j] + sh[c0 + j];
        r[j] = (t > 0.0f) ? t : expm1f(t);
    }
    float4 o; o.x = r[0]; o.y = r[1]; o.z = r[2]; o.w = r[3];
    ((float4*)y)[i] = o;
}

extern "C" void kernel_launch(void* const* d_in, const int* in_sizes, int n_in,
                              void* d_out, int out_size, void* d_ws, size_t ws_size,
                              hipStream_t stream) {
    const float* x     = (const float*)d_in[0];
    const int*   neigh = (const int*)d_in[1];
    const float* w     = (const float*)d_in[2];
    const float* gamma = (const float*)d_in[3];
    const float* beta  = (const float*)d_in[4];
    float* y  = (float*)d_out;
    float* st = (float*)((char*)d_ws + WS_STAT_OFF);

    // zero the 32 slot-sets (8 KB)
    hipMemsetAsync(st, 0, NSLOTS * 64 * sizeof(float), stream);

    if (ws_size >= WS_NEED) {
        unsigned short* wbp = (unsigned short*)((char*)d_ws + WS_WB_OFF);
        unsigned short* xb  = (unsigned short*)((char*)d_ws + WS_XB_OFF);

        prep_kernel<<<CVT_BLOCKS + PACK_BLOCKS, 256, 0, stream>>>(x, xb, w, wbp);

        int convBlocks = (NN + 63) / 64;
        conv_mfma_kernel<<<convBlocks, 256, 0, stream>>>(xb, neigh, wbp, y, st);
    } else {
        int convBlocks = (NN + 255) / 256;
        conv_kernel<<<convBlocks, 256, 0, stream>>>(x, neigh, w, y);
        stats_kernel<<<512, 256, 0, stream>>>(y, st);
    }

    size_t total4 = (size_t)NN * COUT / 4;
    bn_elu_kernel<<<(int)((total4 + 255) / 256), 256, 0, stream>>>(y, st, gamma, beta);
}